// Round 11
// baseline (91.155 us; speedup 1.0000x reference)
//
#include <hip/hip_runtime.h>
#include <math.h>

// FusedAttentionWithRPB round 11: barrier-free main loop.
//  - 32x32 swapped MFMA (r10 math, refcheck'd) with KA fragments loaded
//    GLOBAL-DIRECT from L2-resident ws (no LDS staging, no per-step barrier)
//  - LDS = 1KB (BZ2 only) -> occupancy VGPR-limited; __launch_bounds__(128,4)
//  - 1632 chunk-blocks (<=3 steps, LPT), bh%8 XCD pinning via j&31=bh
//  - v_cvt_pk_bf16_f32 packing; T13 defer-max (THR=8)
//  - prep_vt transposes via LDS staging (coalesced V reads)

constexpr int Bc = 4, Hc = 8, Sc = 1024, Dc = 64;

constexpr size_t KA_BYTES   = (size_t)32 * 1024 * 256;            // 8 MB
constexpr size_t VT_BYTES   = (size_t)32 * 16 * 64 * 128;         // 4 MB
constexpr size_t PART_OFF   = KA_BYTES + VT_BYTES;
constexpr size_t PART_BYTES = (size_t)32 * 13 * 6 * 64 * 68 * sizeof(float);
constexpr size_t WS_SPLIT   = PART_OFF + PART_BYTES;

typedef __attribute__((ext_vector_type(8)))  short bf16x8;
typedef __attribute__((ext_vector_type(16))) float f32x16;

// chunk tables (51/bh): LPT order — all 3-step chunks, then 2-step, then 1.
__device__ __constant__ signed char CQI[51] =
  {15,15,15,15, 14,14,14,14,14, 13,13,13,13, 12,12,12, 11,11,11,11, 10,10,10,
    9,9, 8,8,8, 7,7, 6, 5,5, 4, 2,
   15,15, 13, 12,12, 10, 9,9, 7, 6,6, 4, 3,3, 1, 0};
__device__ __constant__ signed char CKTB[51] =
  { 0,3,6,9, 0,3,6,9,12, 0,3,6,9, 0,3,6, 0,3,6,9, 0,3,6,
    0,3, 0,3,6, 0,3, 0, 0,3, 0, 0,
   12,14, 12, 9,11, 9, 6,8, 6, 3,5, 3, 0,2, 0, 0};
__device__ __constant__ signed char CKTE[51] =
  { 3,6,9,12, 3,6,9,12,15, 3,6,9,12, 3,6,9, 3,6,9,12, 3,6,9,
    3,6, 3,6,9, 3,6, 3, 3,6, 3, 3,
   14,16, 14, 11,13, 11, 8,10, 8, 5,7, 5, 2,4, 2, 1};
__device__ __constant__ signed char CPT[51] =
  { 0,1,2,3, 0,1,2,3,4, 0,1,2,3, 0,1,2, 0,1,2,3, 0,1,2,
    0,1, 0,1,2, 0,1, 0, 0,1, 0, 0,
    4,5, 4, 3,4, 3, 2,3, 2, 1,2, 1, 0,1, 0, 0};
__device__ __constant__ signed char NPT[13] = {2,2,2,3,3,3,4,4,4,5,5,5,6};

__device__ __forceinline__ unsigned cvtpk(float a, float b) {
  unsigned r;
  asm("v_cvt_pk_bf16_f32 %0, %1, %2" : "=v"(r) : "v"(a), "v"(b));
  return r;   // lo16 = bf16(a), hi16 = bf16(b)
}
__device__ __forceinline__ unsigned short f2bf(float f) {
  union { float f; unsigned u; } x; x.f = f;
  unsigned r = x.u + 0x7FFFu + ((x.u >> 16) & 1u);
  return (unsigned short)(r >> 16);
}
__device__ __forceinline__ bf16x8 pack8(float4 a, float4 b) {
  union { unsigned u[4]; bf16x8 v; } r;
  r.u[0] = cvtpk(a.x, a.y); r.u[1] = cvtpk(a.z, a.w);
  r.u[2] = cvtpk(b.x, b.y); r.u[3] = cvtpk(b.z, b.w);
  return r.v;
}
__device__ __forceinline__ float4 sc4(float4 a, float s) {
  return make_float4(a.x*s, a.y*s, a.z*s, a.w*s);
}

// ---- fused pre-pass: blocks 0-511 KA rows, 512-1023 Vt tiles.
// KA row (bh,key): 16 slots of 16B; logical 0-7 = K dims, 8-11 = x-bias cols,
// 12-15 = y-bias cols; physical slot = logical ^ (key&7).
// Vt row (bh,tile,d): 8 slots of 16B; logical s = keys [8s,8s+8); phys = s^(d&7).
__global__ __launch_bounds__(256) void prep(
    const float* __restrict__ kg, const float* __restrict__ vg,
    const int* __restrict__ px, const int* __restrict__ py,
    const float* __restrict__ bx, const float* __restrict__ by,
    unsigned short* __restrict__ wsKA, unsigned short* __restrict__ wsVt)
{
  __shared__ float tile[64 * 68];
  const int t = threadIdx.x;
  if (blockIdx.x < 512) {
    const int g = blockIdx.x * 64 + (t >> 2);
    const int p = t & 3;
    const int bh = g >> 10, key = g & 1023;
    const int b = bh >> 3, h = bh & 7;
    const float* ksrc = kg + ((size_t)bh * Sc + key) * Dc + p * 16;
    float4 f0 = ((const float4*)ksrc)[0], f1 = ((const float4*)ksrc)[1];
    float4 f2 = ((const float4*)ksrc)[2], f3 = ((const float4*)ksrc)[3];
    unsigned short* rowp = wsKA + (size_t)g * 128;
    const int rx = key & 7;
    *(bf16x8*)(rowp + (((2*p)   ^ rx) << 3)) = pack8(f0, f1);
    *(bf16x8*)(rowp + (((2*p+1) ^ rx) << 3)) = pack8(f2, f3);
    const int kx = px[b * Sc + key], ky = py[b * Sc + key];
    bf16x8 xv, yv;
    #pragma unroll
    for (int m = 0; m < 8; ++m) {
      int ix = 8*p + m - kx; ix = ix < -30 ? -30 : (ix > 30 ? 30 : ix);
      int iy = 8*p + m - ky; iy = iy < -30 ? -30 : (iy > 30 ? 30 : iy);
      xv[m] = (short)f2bf(bx[(ix + 30) * Hc + h]);
      yv[m] = (short)f2bf(by[(iy + 30) * Hc + h]);
    }
    *(bf16x8*)(rowp + (((8  + p) ^ rx) << 3)) = xv;
    *(bf16x8*)(rowp + (((12 + p) ^ rx) << 3)) = yv;
  } else {
    const int bid = blockIdx.x - 512;
    const int bh = bid >> 4, tt = bid & 15;
    // coalesced read of the 64x64 f32 V tile into LDS
    const int row = t >> 2, c4 = t & 3;
    const float4* src = (const float4*)(vg + ((size_t)bh * Sc + tt*64 + row) * Dc + c4*16);
    #pragma unroll
    for (int jj = 0; jj < 4; ++jj)
      *(float4*)&tile[row * 68 + c4*16 + 4*jj] = src[jj];
    __syncthreads();
    // transposed write: thread (d, chunk-group)
    const int d = t & 63, cg = t >> 6;
    unsigned short* rowp = wsVt + (((size_t)bh * 16 + tt) * 64 + d) * 64;
    #pragma unroll
    for (int cc = 0; cc < 2; ++cc) {
      const int c = 2*cg + cc;
      union { unsigned u[4]; uint4 q; } vv;
      #pragma unroll
      for (int jj = 0; jj < 4; ++jj)
        vv.u[jj] = cvtpk(tile[(8*c + 2*jj) * 68 + d], tile[(8*c + 2*jj + 1) * 68 + d]);
      *(uint4*)(rowp + ((c ^ (d & 7)) << 3)) = vv.q;
    }
  }
}

// ---- main kernel: 128 threads, 2 waves, no per-step barrier
__global__ __launch_bounds__(128, 4) void attn_rpb_mfma10(
    const float* __restrict__ qg,
    const int* __restrict__ px, const int* __restrict__ py, const int* __restrict__ pz,
    const float* __restrict__ bz,
    const unsigned short* __restrict__ wsKA, const unsigned short* __restrict__ wsVt,
    float* __restrict__ outg, float* __restrict__ wsPart, int mode)
{
  int qi, ktb, kte, part, np, bh;
  {
    const int j = blockIdx.x;
    if (mode == 0) {
      const int idx = j & 255; bh = idx >> 3; const int r3 = idx & 7;
      qi = (j < 256) ? (15 - r3) : r3;
      ktb = 0; kte = qi + 1; part = 0; np = 1;
    } else {
      bh = j & 31;
      const int cid = j >> 5;
      qi = CQI[cid]; ktb = CKTB[cid]; kte = CKTE[cid]; part = CPT[cid];
      np = (qi + 3) / 3;   // ceil((qi+1)/3)
    }
  }
  const int h = bh & 7, b = bh >> 3;

  __shared__ float BZ2[256];

  const int t   = threadIdx.x;
  const int w2  = t >> 6;        // wave 0..1 -> q rows [32w2, 32w2+32)
  const int l   = t & 63;
  const int q32 = l & 31;        // q-local (C/D col)
  const int hi  = l >> 5;        // k-half selector
  const int rx  = q32 & 7;
  const size_t bhOff = (size_t)bh * Sc;
  const int q0 = qi * 64;
  const int myq = q0 + 32*w2 + q32;

  const char* kaSrc = (const char*)wsKA;
  const char* vtSrc = (const char*)wsVt;

  // ---- prologue: BZ2 table; Q/one-hot B-frags -> regs
  #pragma unroll
  for (int e = t; e < 256; e += 128) {
    int dzz = (e >> 4) - (e & 15); dzz = dzz < -10 ? -10 : (dzz > 10 ? 10 : dzz);
    BZ2[e] = bz[(dzz + 10) * Hc + h];
  }
  bf16x8 qf[8];   // B-frags: B[k=16ks+8hi+i][col=q32]
  {
    const float* qrow = qg + (bhOff + myq) * Dc;
    #pragma unroll
    for (int ks = 0; ks < 4; ++ks) {
      float4 f0 = *(const float4*)(qrow + 16*ks + 8*hi);
      float4 f1 = *(const float4*)(qrow + 16*ks + 8*hi + 4);
      qf[ks] = pack8(sc4(f0, 0.125f), sc4(f1, 0.125f));
    }
    const int qxr = px[b*Sc + myq], qyr = py[b*Sc + myq];
    const short one = (short)0x3F80;
    #pragma unroll
    for (int m = 0; m < 8; ++m) {
      qf[4][m] = (qxr ==      8*hi + m) ? one : (short)0;
      qf[5][m] = (qxr == 16 + 8*hi + m) ? one : (short)0;
      qf[6][m] = (qyr ==      8*hi + m) ? one : (short)0;
      qf[7][m] = (qyr == 16 + 8*hi + m) ? one : (short)0;
    }
  }
  const int qz16 = pz[b*Sc + myq] << 4;

  float mrow = -INFINITY, lsum = 0.0f;
  f32x16 O2[2];
  #pragma unroll
  for (int nt2 = 0; nt2 < 2; ++nt2)
    #pragma unroll
    for (int r = 0; r < 16; ++r) O2[nt2][r] = 0.0f;

  __syncthreads();   // BZ2 visible (only barrier in the kernel)

  for (int kt = ktb; kt < kte; ++kt) {
    const int k0 = kt * 64;
    const char* kaTile = kaSrc + ((size_t)(bh*1024 + k0)) * 256;
    const char* vtile  = vtSrc + ((size_t)(bh*16 + kt)) * 8192;

    // ---- V A-frags + kz -> regs (issue early; L2-resident)
    bf16x8 vf[2][4];
    #pragma unroll
    for (int nt2 = 0; nt2 < 2; ++nt2) {
      const int d = 32*nt2 + q32;
      const char* vrow = vtile + d * 128;
      const int dx = d & 7;
      #pragma unroll
      for (int c4 = 0; c4 < 4; ++c4)
        vf[nt2][c4] = *(const bf16x8*)(vrow + (((2*c4 + hi) ^ dx) << 4));
    }
    int kzv[2][4][4];
    #pragma unroll
    for (int kk = 0; kk < 2; ++kk)
      #pragma unroll
      for (int g = 0; g < 4; ++g) {
        int4 k4 = *(const int4*)(pz + b*Sc + k0 + 32*kk + 8*g + 4*hi);
        kzv[kk][g][0] = k4.x; kzv[kk][g][1] = k4.y;
        kzv[kk][g][2] = k4.z; kzv[kk][g][3] = k4.w;
      }

    // ---- S^T = KA x Q : fragments straight from global (L2)
    f32x16 s2[2];
    #pragma unroll
    for (int kk = 0; kk < 2; ++kk) {
      #pragma unroll
      for (int r = 0; r < 16; ++r) s2[kk][r] = 0.0f;
      const char* base = kaTile + (32*kk + q32) * 256;
      #pragma unroll
      for (int ks = 0; ks < 8; ++ks) {
        bf16x8 af = *(const bf16x8*)(base + (((2*ks + hi) ^ rx) << 4));
        s2[kk] = __builtin_amdgcn_mfma_f32_32x32x16_bf16(af, qf[ks], s2[kk], 0, 0, 0);
      }
    }

    // ---- z-bias (+ causal mask on diag tile)
    const bool diag = (kt == qi);
    #pragma unroll
    for (int kk = 0; kk < 2; ++kk) {
      #pragma unroll
      for (int r = 0; r < 16; ++r) {
        float val = s2[kk][r] + BZ2[qz16 | kzv[kk][r>>2][r&3]];
        if (diag) {
          const int key = k0 + 32*kk + (r&3) + 8*(r>>2) + 4*hi;
          if (key > myq) val = -INFINITY;
        }
        s2[kk][r] = val;
      }
    }

    // ---- lane-local online softmax with defer-max (T13, THR=8)
    float tmax = s2[0][0];
    #pragma unroll
    for (int kk = 0; kk < 2; ++kk)
      #pragma unroll
      for (int r = 0; r < 16; ++r) tmax = fmaxf(tmax, s2[kk][r]);
    tmax = fmaxf(tmax, __shfl_xor(tmax, 32));
    if (!__all(tmax - mrow <= 8.0f)) {
      const float mn = fmaxf(mrow, tmax);
      const float alpha = __expf(mrow - mn);
      mrow = mn;
      lsum *= alpha;
      #pragma unroll
      for (int nt2 = 0; nt2 < 2; ++nt2)
        #pragma unroll
        for (int r = 0; r < 16; ++r) O2[nt2][r] *= alpha;
    }
    float ps = 0.0f;
    #pragma unroll
    for (int kk = 0; kk < 2; ++kk)
      #pragma unroll
      for (int r = 0; r < 16; ++r) {
        const float p = __expf(s2[kk][r] - mrow);
        s2[kk][r] = p;
        ps += p;
      }
    ps += __shfl_xor(ps, 32);
    lsum += ps;

    // ---- P -> bf16 B-frags in-register (cvt_pk + shfl + select)
    unsigned pk[2][8], sw[2][8];
    #pragma unroll
    for (int kk = 0; kk < 2; ++kk)
      #pragma unroll
      for (int jj = 0; jj < 8; ++jj) {
        pk[kk][jj] = cvtpk(s2[kk][2*jj], s2[kk][2*jj + 1]);
        sw[kk][jj] = __shfl_xor((int)pk[kk][jj], 32);
      }

    // ---- O^T += Vt x P
    #pragma unroll
    for (int kk = 0; kk < 2; ++kk) {
      #pragma unroll
      for (int ks2 = 0; ks2 < 2; ++ks2) {
        union { unsigned u[4]; bf16x8 v; } pf_;
        pf_.u[0] = hi ? sw[kk][4*ks2 + 2] : pk[kk][4*ks2];
        pf_.u[1] = hi ? sw[kk][4*ks2 + 3] : pk[kk][4*ks2 + 1];
        pf_.u[2] = hi ? pk[kk][4*ks2 + 2] : sw[kk][4*ks2];
        pf_.u[3] = hi ? pk[kk][4*ks2 + 3] : sw[kk][4*ks2 + 1];
        const int c4 = 2*kk + ks2;
        #pragma unroll
        for (int nt2 = 0; nt2 < 2; ++nt2)
          O2[nt2] = __builtin_amdgcn_mfma_f32_32x32x16_bf16(vf[nt2][c4], pf_.v, O2[nt2], 0, 0, 0);
      }
    }
  }

  // ---- epilogue: lane owns q=myq column; d = 32nt2 + (r&3) + 8*(r>>2) + 4hi
  if (np == 1) {
    const float inv = 1.0f / lsum;
    float* orow = outg + (bhOff + myq) * Dc;
    #pragma unroll
    for (int nt2 = 0; nt2 < 2; ++nt2)
      #pragma unroll
      for (int jq = 0; jq < 4; ++jq) {
        float4 o4 = make_float4(O2[nt2][4*jq]*inv,   O2[nt2][4*jq+1]*inv,
                                O2[nt2][4*jq+2]*inv, O2[nt2][4*jq+3]*inv);
        *(float4*)(orow + 32*nt2 + 8*jq + 4*hi) = o4;
      }
  } else {
    float* rowp = wsPart + ((((size_t)bh * 13 + (qi - 3)) * 6 + part) * 64
                            + 32*w2 + q32) * 68;
    #pragma unroll
    for (int nt2 = 0; nt2 < 2; ++nt2)
      #pragma unroll
      for (int jq = 0; jq < 4; ++jq) {
        float4 o4 = make_float4(O2[nt2][4*jq],   O2[nt2][4*jq+1],
                                O2[nt2][4*jq+2], O2[nt2][4*jq+3]);
        *(float4*)(rowp + 32*nt2 + 8*jq + 4*hi) = o4;
      }
    if (hi == 0) { rowp[64] = mrow; rowp[65] = lsum; }
  }
}

// merge np partials per (bh, qi>=3) row; partial row pitch 68
__global__ __launch_bounds__(256) void attn_rpb_combine(
    const float* __restrict__ wsPart, float* __restrict__ outg)
{
  const int t = threadIdx.x;
  const int ridx = blockIdx.x * 4 + (t >> 6);   // 0..26623
  const int d = t & 63;
  const int bh = ridx / 832;                    // 13*64
  const int rem = ridx - bh * 832;
  const int qj = rem >> 6;                      // 0..12 -> qi = qj+3
  const int rl = rem & 63;
  const int np = NPT[qj];
  const float* base = wsPart + (((size_t)bh * 13 + qj) * 6) * 64 * 68 + (size_t)rl * 68;
  float m = -INFINITY;
  for (int p = 0; p < np; ++p) m = fmaxf(m, base[p * 4352 + 64]);
  float lc = 0.0f, o = 0.0f;
  for (int p = 0; p < np; ++p) {
    const float wp = __expf(base[p * 4352 + 64] - m);
    lc += base[p * 4352 + 65] * wp;
    o  += base[p * 4352 + d] * wp;
  }
  outg[((size_t)bh * Sc + (qj + 3) * 64 + rl) * Dc + d] = o / lc;
}

extern "C" void kernel_launch(void* const* d_in, const int* in_sizes, int n_in,
                              void* d_out, int out_size, void* d_ws, size_t ws_size,
                              hipStream_t stream) {
  const float* q  = (const float*)d_in[0];
  const float* k  = (const float*)d_in[1];
  const float* v  = (const float*)d_in[2];
  const int*   px = (const int*)d_in[3];
  const int*   py = (const int*)d_in[4];
  const int*   pz = (const int*)d_in[5];
  const float* bx = (const float*)d_in[6];
  const float* by = (const float*)d_in[7];
  const float* bz = (const float*)d_in[8];
  float* out = (float*)d_out;

  unsigned short* wsKA = (unsigned short*)d_ws;
  unsigned short* wsVt = (unsigned short*)((char*)d_ws + KA_BYTES);
  float* wsPart = (float*)((char*)d_ws + PART_OFF);

  prep<<<1024, 256, 0, stream>>>(k, v, px, py, bx, by, wsKA, wsVt);

  if (ws_size >= WS_SPLIT) {
    attn_rpb_mfma10<<<51 * 32, 128, 0, stream>>>(q, px, py, pz, bz, wsKA, wsVt, out, wsPart, 1);
    attn_rpb_combine<<<6656, 256, 0, stream>>>(wsPart, out);
  } else {
    attn_rpb_mfma10<<<512, 128, 0, stream>>>(q, px, py, pz, bz, wsKA, wsVt, out, wsPart, 0);
  }
}